// Round 2
// baseline (708.130 us; speedup 1.0000x reference)
//
#include <hip/hip_runtime.h>

// CARAFE naive upsample: N=2, C=256, H=100, W=100, K=5, G=1, S=2.
// out[n,c,2h+a,2w+b] = sum_{dy,dx} mask[n,dy*5+dx,2h+a,2w+b] * feat[n,c,h+dy-2,w+dx-2]
// (zero-padded features outside [0,H)x[0,W)).
//
// Thread -> one low-res pixel (h,w) x 8-channel chunk -> 2x2 output quad for
// those 8 channels. Mask loads (2x float2 per tap) amortized over 8 channels;
// feature loads reused over 4 outputs.
//
// R1: VGPR was 256 -> 2 waves/SIMD, latency-bound (VALUBusy 18%, occupancy
// 11%). Cap registers with __launch_bounds__(256,4) and use 32-bit offset
// arithmetic throughout.

#define N_ 2
#define C_ 256
#define H_ 100
#define W_ 100
#define KK_ 25
#define CC 8
#define HW_ (H_ * W_)
#define OW_ (W_ * 2)
#define OHW_ (HW_ * 4)
#define NCHUNK (C_ / CC)
#define SPATIAL_BLOCKS ((HW_ + 255) / 256)   // 40

__global__ __launch_bounds__(256, 4) void carafe_kernel(
    const float* __restrict__ feat,
    const float* __restrict__ mask,
    float* __restrict__ out) {

    int b = blockIdx.x;
    int sb = b % SPATIAL_BLOCKS;
    int rest = b / SPATIAL_BLOCKS;
    int cchunk = rest % NCHUNK;
    int n = rest / NCHUNK;

    int idx = sb * 256 + threadIdx.x;
    if (idx >= HW_) return;
    int h = idx / W_;
    int w = idx % W_;

    float acc[CC][4];
#pragma unroll
    for (int c = 0; c < CC; ++c) {
        acc[c][0] = 0.f; acc[c][1] = 0.f; acc[c][2] = 0.f; acc[c][3] = 0.f;
    }

    // 32-bit offsets; per-n / per-chunk bases folded into the pointers once.
    const float* mbase = mask + n * (KK_ * OHW_) + (2 * h) * OW_ + (2 * w);
    const float* fbase = feat + (n * C_ + cchunk * CC) * HW_;

#pragma unroll
    for (int dy = 0; dy < 5; ++dy) {
        const int y = h + dy - 2;
        const bool yv = (unsigned)y < (unsigned)H_;
        const int frow = y * W_ + w - 2;
#pragma unroll
        for (int dx = 0; dx < 5; ++dx) {
            const int tap = dy * 5 + dx;
            const int x = w + dx - 2;
            const bool valid = yv & ((unsigned)x < (unsigned)W_);

            const float* mrow = mbase + tap * OHW_;
            float2 m0 = *reinterpret_cast<const float2*>(mrow);        // a=0
            float2 m1 = *reinterpret_cast<const float2*>(mrow + OW_);  // a=1

            const int foff = frow + dx;
#pragma unroll
            for (int c = 0; c < CC; ++c) {
                float f = valid ? fbase[c * HW_ + foff] : 0.f;
                acc[c][0] += f * m0.x;
                acc[c][1] += f * m0.y;
                acc[c][2] += f * m1.x;
                acc[c][3] += f * m1.y;
            }
        }
    }

    float* obase = out + (n * C_ + cchunk * CC) * OHW_ + (2 * h) * OW_ + (2 * w);
#pragma unroll
    for (int c = 0; c < CC; ++c) {
        *reinterpret_cast<float2*>(obase + c * OHW_) =
            make_float2(acc[c][0], acc[c][1]);
        *reinterpret_cast<float2*>(obase + c * OHW_ + OW_) =
            make_float2(acc[c][2], acc[c][3]);
    }
}

extern "C" void kernel_launch(void* const* d_in, const int* in_sizes, int n_in,
                              void* d_out, int out_size, void* d_ws, size_t ws_size,
                              hipStream_t stream) {
    const float* feat = (const float*)d_in[0];
    const float* mask = (const float*)d_in[1];
    float* out = (float*)d_out;

    const int grid = N_ * NCHUNK * SPATIAL_BLOCKS;  // 2 * 32 * 40 = 2560
    carafe_kernel<<<grid, 256, 0, stream>>>(feat, mask, out);
}

// Round 3
// 50.085 us; speedup vs baseline: 14.1386x; 14.1386x over previous
//
#include <hip/hip_runtime.h>

// CARAFE naive upsample: N=2, C=256, H=100, W=100, K=5, G=1, S=2.
// out[n,c,2h+a,2w+b] = sum_{dy,dx} mask[n,dy*5+dx,2h+a,2w+b] * feat[n,c,h+dy-2,w+dx-2]
//
// Thread -> one low-res pixel (h,w) x 8-channel chunk -> 2x2 output quad for
// those 8 channels.
//
// R1: full 25-tap unroll -> compiler hoisted ~300 loads -> 256 VGPR, 2
//     waves/SIMD, latency-bound (VALUBusy 18%). 80.7 us.
// R2: __launch_bounds__(256,4) cap -> acc spilled to scratch (FETCH 578 MB,
//     WRITE 1.1 GB of spill traffic). 708 us. Never cap below the live set.
// R3: keep CC=8, unroll only the dx row (5 taps of ILP), '#pragma unroll 1'
//     on dy so only one row's loads are in flight. Natural VGPR ~100-128.

#define N_ 2
#define C_ 256
#define H_ 100
#define W_ 100
#define CC 8
#define HW_ (H_ * W_)
#define OW_ (W_ * 2)
#define OHW_ (HW_ * 4)
#define NCHUNK (C_ / CC)
#define SPATIAL_BLOCKS ((HW_ + 255) / 256)   // 40

__global__ __launch_bounds__(256) void carafe_kernel(
    const float* __restrict__ feat,
    const float* __restrict__ mask,
    float* __restrict__ out) {

    int b = blockIdx.x;
    int sb = b % SPATIAL_BLOCKS;
    int rest = b / SPATIAL_BLOCKS;
    int cchunk = rest % NCHUNK;
    int n = rest / NCHUNK;

    int idx = sb * 256 + threadIdx.x;
    if (idx >= HW_) return;
    int h = idx / W_;
    int w = idx % W_;

    float acc[CC][4];
#pragma unroll
    for (int c = 0; c < CC; ++c) {
        acc[c][0] = 0.f; acc[c][1] = 0.f; acc[c][2] = 0.f; acc[c][3] = 0.f;
    }

    const float* mbase = mask + n * (25 * OHW_) + (2 * h) * OW_ + (2 * w);
    const float* fbase = feat + (n * C_ + cchunk * CC) * HW_;

#pragma unroll 1
    for (int dy = 0; dy < 5; ++dy) {
        const int y = h + dy - 2;
        const bool yv = (unsigned)y < (unsigned)H_;
        const int frow = y * W_ + w - 2;
        const float* mrow_dy = mbase + (dy * 5) * OHW_;

#pragma unroll
        for (int dx = 0; dx < 5; ++dx) {
            const int x = w + dx - 2;
            const bool valid = yv & ((unsigned)x < (unsigned)W_);

            const float* mrow = mrow_dy + dx * OHW_;
            float2 m0 = *reinterpret_cast<const float2*>(mrow);        // a=0
            float2 m1 = *reinterpret_cast<const float2*>(mrow + OW_);  // a=1

            const int foff = frow + dx;
#pragma unroll
            for (int c = 0; c < CC; ++c) {
                float f = valid ? fbase[c * HW_ + foff] : 0.f;
                acc[c][0] += f * m0.x;
                acc[c][1] += f * m0.y;
                acc[c][2] += f * m1.x;
                acc[c][3] += f * m1.y;
            }
        }
    }

    float* obase = out + (n * C_ + cchunk * CC) * OHW_ + (2 * h) * OW_ + (2 * w);
#pragma unroll
    for (int c = 0; c < CC; ++c) {
        *reinterpret_cast<float2*>(obase + c * OHW_) =
            make_float2(acc[c][0], acc[c][1]);
        *reinterpret_cast<float2*>(obase + c * OHW_ + OW_) =
            make_float2(acc[c][2], acc[c][3]);
    }
}

extern "C" void kernel_launch(void* const* d_in, const int* in_sizes, int n_in,
                              void* d_out, int out_size, void* d_ws, size_t ws_size,
                              hipStream_t stream) {
    const float* feat = (const float*)d_in[0];
    const float* mask = (const float*)d_in[1];
    float* out = (float*)d_out;

    const int grid = N_ * NCHUNK * SPATIAL_BLOCKS;  // 2 * 32 * 40 = 2560
    carafe_kernel<<<grid, 256, 0, stream>>>(feat, mask, out);
}

// Round 4
// 47.248 us; speedup vs baseline: 14.9875x; 1.0600x over previous
//
#include <hip/hip_runtime.h>

// CARAFE naive upsample: N=2, C=256, H=100, W=100, K=5, G=1, S=2.
// out[n,c,2h+a,2w+b] = sum_{dy,dx} mask[n,dy*5+dx,2h+a,2w+b] * feat[n,c,h+dy-2,w+dx-2]
//
// Thread -> one low-res pixel (h,w) x 8-channel chunk -> 2x2 output quad.
//
// R1: full 25-tap unroll -> 256 VGPR, latency-bound. 80.7 us.
// R2: (256,4) cap -> scratch spills (1.6 GB traffic). 708 us.
// R3: unroll-1 dy row loop, VGPR 72. 50.1 us. VALUBusy 28%, HBM 22% -> still
//     latency/overhead-bound; VALU busy-time ~18.5 us vs ~6.5 us FMA floor.
// R4: (a) clamp feature coords (v_med3) + zero the MASK on invalid taps
//     (4 cndmask/tap instead of 8 per-load selects); (b) float2 accumulators
//     with shared broadcast feature -> v_pk_fma_f32 packing; (c) unroll 2 on
//     dy for 2 rows of loads in flight.

#define N_ 2
#define C_ 256
#define H_ 100
#define W_ 100
#define CC 8
#define HW_ (H_ * W_)
#define OW_ (W_ * 2)
#define OHW_ (HW_ * 4)
#define NCHUNK (C_ / CC)
#define SPATIAL_BLOCKS ((HW_ + 255) / 256)   // 40

__global__ __launch_bounds__(256) void carafe_kernel(
    const float* __restrict__ feat,
    const float* __restrict__ mask,
    float* __restrict__ out) {

    int b = blockIdx.x;
    int sb = b % SPATIAL_BLOCKS;
    int rest = b / SPATIAL_BLOCKS;
    int cchunk = rest % NCHUNK;
    int n = rest / NCHUNK;

    int idx = sb * 256 + threadIdx.x;
    if (idx >= HW_) return;
    int h = idx / W_;
    int w = idx % W_;

    float2 acc0[CC];   // output row a=0, columns (b=0, b=1)
    float2 acc1[CC];   // output row a=1
#pragma unroll
    for (int c = 0; c < CC; ++c) {
        acc0[c] = make_float2(0.f, 0.f);
        acc1[c] = make_float2(0.f, 0.f);
    }

    const float* mbase = mask + n * (25 * OHW_) + (2 * h) * OW_ + (2 * w);
    const float* fbase = feat + (n * C_ + cchunk * CC) * HW_;

#pragma unroll 2
    for (int dy = 0; dy < 5; ++dy) {
        const int y = h + dy - 2;
        const bool yv = (unsigned)y < (unsigned)H_;
        const int yc = min(max(y, 0), H_ - 1);       // v_med3_i32
        const int rowb = yc * W_;
        const float* mrow_dy = mbase + (dy * 5) * OHW_;

#pragma unroll
        for (int dx = 0; dx < 5; ++dx) {
            const int x = w + dx - 2;
            const bool v = yv && ((unsigned)x < (unsigned)W_);
            const int xc = min(max(x, 0), W_ - 1);   // v_med3_i32

            const float* mrow = mrow_dy + dx * OHW_;
            float2 m0 = *reinterpret_cast<const float2*>(mrow);        // a=0
            float2 m1 = *reinterpret_cast<const float2*>(mrow + OW_);  // a=1
            // Zero the mask (4 selects) instead of predicating 8 feature loads.
            if (!v) { m0 = make_float2(0.f, 0.f); m1 = make_float2(0.f, 0.f); }

            const int foff = rowb + xc;  // always in-bounds
#pragma unroll
            for (int c = 0; c < CC; ++c) {
                const float f = fbase[c * HW_ + foff];
                acc0[c].x = fmaf(f, m0.x, acc0[c].x);
                acc0[c].y = fmaf(f, m0.y, acc0[c].y);
                acc1[c].x = fmaf(f, m1.x, acc1[c].x);
                acc1[c].y = fmaf(f, m1.y, acc1[c].y);
            }
        }
    }

    float* obase = out + (n * C_ + cchunk * CC) * OHW_ + (2 * h) * OW_ + (2 * w);
#pragma unroll
    for (int c = 0; c < CC; ++c) {
        *reinterpret_cast<float2*>(obase + c * OHW_) = acc0[c];
        *reinterpret_cast<float2*>(obase + c * OHW_ + OW_) = acc1[c];
    }
}

extern "C" void kernel_launch(void* const* d_in, const int* in_sizes, int n_in,
                              void* d_out, int out_size, void* d_ws, size_t ws_size,
                              hipStream_t stream) {
    const float* feat = (const float*)d_in[0];
    const float* mask = (const float*)d_in[1];
    float* out = (float*)d_out;

    const int grid = N_ * NCHUNK * SPATIAL_BLOCKS;  // 2 * 32 * 40 = 2560
    carafe_kernel<<<grid, 256, 0, stream>>>(feat, mask, out);
}

// Round 5
// 45.249 us; speedup vs baseline: 15.6495x; 1.0442x over previous
//
#include <hip/hip_runtime.h>

// CARAFE naive upsample: N=2, C=256, H=100, W=100, K=5, G=1, S=2.
// out[n,c,2h+a,2w+b] = sum_{dy,dx} mask[n,dy*5+dx,2h+a,2w+b] * feat[n,c,h+dy-2,w+dx-2]
//
// R1: full 25-tap unroll -> 256 VGPR, latency-bound. 80.7 us.
// R2: (256,4) cap -> scratch spills (1.6 GB traffic). 708 us.
// R3: unroll-1 dy loop, VGPR 72. 50.1 us.
// R4: clamp+mask-zero, pk-fma accs. 47.2 us. VALUBusy 27%, HBM 23% -> bound
//     by L1/L2: channel-strided feature loads (40KB apart) thrash 32KB L1;
//     ~770 MB through L1 (~16-20 us of 64B/clk L1 BW) + latency exposure.
// R5: LDS-stage feature tiles channels-last. Block = (n, cchunk, 10x25 tile).
//     LDS layout [y][c/4][x][c%4]: one tap's 8 channels = 2x ds_read_b128,
//     consecutive-lane 16B stride = conflict-free. Halo zero-filled at
//     staging -> branchless inner loop. Feature L1 traffic drops 25x.

#define N_ 2
#define C_ 256
#define H_ 100
#define W_ 100
#define CC 8
#define HW_ (H_ * W_)
#define OW_ (W_ * 2)
#define OHW_ (HW_ * 4)
#define NCHUNK (C_ / CC)          // 32
#define TH 10
#define TW 25
#define HY (TH + 4)               // 14 halo rows
#define HX (TW + 4)               // 29 halo cols
#define XP 32                     // padded x extent (float4 units)
#define TILES_X (W_ / TW)         // 4
#define TILES_Y (H_ / TH)         // 10

__global__ __launch_bounds__(256) void carafe_kernel(
    const float* __restrict__ feat,
    const float* __restrict__ mask,
    float* __restrict__ out) {

    // [y][cq][x][cl] as float4 units: index (y*2+cq)*XP + x
    __shared__ float lds[HY * 2 * XP * 4];

    const int tile = blockIdx.x;
    const int tx = tile % TILES_X;
    const int ty = tile / TILES_X;
    const int cchunk = blockIdx.y;
    const int n = blockIdx.z;
    const int x0 = tx * TW;
    const int y0 = ty * TH;
    const int t = threadIdx.x;

    // ---- stage features (channels-last, zero-filled halo) ----
    const int lane = t & 31;
    const int g = t >> 5;                       // 8 groups of 32 lanes
    const float* fbase = feat + (n * C_ + cchunk * CC) * HW_;

#pragma unroll
    for (int r = 0; r < 14; ++r) {              // 112 (c,y) pairs / 8 groups
        const int p = r * 8 + g;
        const int c = p / HY;                   // 0..7
        const int y = p % HY;                   // 0..13
        const int yy = y0 - 2 + y;
        const int xx = x0 - 2 + lane;
        float v = 0.f;
        if (lane < HX && (unsigned)yy < (unsigned)H_ && (unsigned)xx < (unsigned)W_)
            v = fbase[c * HW_ + yy * W_ + xx];
        lds[((y * 2 + (c >> 2)) * XP + lane) * 4 + (c & 3)] = v;
    }
    __syncthreads();

    if (t >= TH * TW) return;                   // 250 compute threads
    const int hl = t / TW;
    const int wl = t % TW;

    float2 a0[CC], a1[CC];
#pragma unroll
    for (int c = 0; c < CC; ++c) {
        a0[c] = make_float2(0.f, 0.f);
        a1[c] = make_float2(0.f, 0.f);
    }

    const float4* lds4 = reinterpret_cast<const float4*>(lds);
    const int oh0 = 2 * (y0 + hl);
    const int ow0 = 2 * (x0 + wl);
    const float* mbase = mask + n * (25 * OHW_) + oh0 * OW_ + ow0;

#pragma unroll 2
    for (int dy = 0; dy < 5; ++dy) {
        const int yl = hl + dy;
#pragma unroll
        for (int dx = 0; dx < 5; ++dx) {
            const int tap = dy * 5 + dx;
            const float* mrow = mbase + tap * OHW_;
            const float2 m0 = *reinterpret_cast<const float2*>(mrow);        // a=0
            const float2 m1 = *reinterpret_cast<const float2*>(mrow + OW_);  // a=1

            const float4 lo = lds4[(yl * 2 + 0) * XP + (wl + dx)];  // c 0..3
            const float4 hi = lds4[(yl * 2 + 1) * XP + (wl + dx)];  // c 4..7
            const float f[8] = {lo.x, lo.y, lo.z, lo.w, hi.x, hi.y, hi.z, hi.w};

#pragma unroll
            for (int c = 0; c < CC; ++c) {
                a0[c].x = fmaf(f[c], m0.x, a0[c].x);
                a0[c].y = fmaf(f[c], m0.y, a0[c].y);
                a1[c].x = fmaf(f[c], m1.x, a1[c].x);
                a1[c].y = fmaf(f[c], m1.y, a1[c].y);
            }
        }
    }

    float* obase = out + (n * C_ + cchunk * CC) * OHW_ + oh0 * OW_ + ow0;
#pragma unroll
    for (int c = 0; c < CC; ++c) {
        *reinterpret_cast<float2*>(obase + c * OHW_) = a0[c];
        *reinterpret_cast<float2*>(obase + c * OHW_ + OW_) = a1[c];
    }
}

extern "C" void kernel_launch(void* const* d_in, const int* in_sizes, int n_in,
                              void* d_out, int out_size, void* d_ws, size_t ws_size,
                              hipStream_t stream) {
    const float* feat = (const float*)d_in[0];
    const float* mask = (const float*)d_in[1];
    float* out = (float*)d_out;

    dim3 grid(TILES_X * TILES_Y, NCHUNK, N_);   // 40 x 32 x 2 = 2560 blocks
    carafe_kernel<<<grid, 256, 0, stream>>>(feat, mask, out);
}